// Round 2
// baseline (397.000 us; speedup 1.0000x reference)
//
#include <hip/hip_runtime.h>

// ---------------------------------------------------------------------------
// DiffAttention forward, bf16 MFMA pipeline.  B=4 T=1024 C=1024 H=16 hs=64 dv=128.
//   1. cast x -> bf16; transpose-cast weights -> W^T[n][k] bf16
//   2. proj GEMM (m97-style global_load_lds): proj[4096][6144] = xb @ wcat^T
//   3. transpose v slice -> vt[(b,h)][dim][key-PERMUTED] (PV-fragment order)
//   4. attention: BARRIER-FREE, LDS-FREE. One 64-thread block = one wave,
//      fully independent. K frags read direct from proj (L2-hit), V frags
//      direct from permuted vt as single b128 loads. Transposed-S chaining:
//      S^T = K Q^T (16x16x32) -> P^T C-frag feeds PV (O^T += V^T P^T,
//      16x16x16) from registers. Softmax per-lane scalar (q = lane&15);
//      row-sum l via ones-row MFMA; defer-rescale (T13). Dispatch: x&7 = XCD,
//      each XCD walks its 8 (b,h) sets two-at-a-time (L2 window ~3MB < 4MB),
//      big-qblk-first (LPT). Fused subLN.
//   5. out GEMM: out[4096][1024] fp32 = yln @ wc^T
// MFMA mappings (HW-verified): A[m=lane&15][k=quad*8+j] (K=32) / quad*4+j
// (K=16); B^T[n=lane&15][k=same]; C/D: col=lane&15, row=quad*4+reg.
// R8 lesson: #else of the MFMA16 guard must be host-safe (host pass sees no
// amdgcn builtins).
// R9 lesson: attn LDS bank conflicts were the b64/b128 aliasing floor.
// R10 (this round): R0->R1 showed occupancy 2->3 blocks/CU bought only 3% ->
// attn was BARRIER/LATENCY-bound, not pipe-bound. Hence the no-LDS rewrite.
// ---------------------------------------------------------------------------

#define T_SEQ 1024
#define NH 16
#define DV 128
#define NPROJ 6144

typedef __bf16 bf16_t;
typedef __bf16 bf16x8 __attribute__((ext_vector_type(8)));
typedef __bf16 bf16x4 __attribute__((ext_vector_type(4)));
typedef short s16x4 __attribute__((ext_vector_type(4)));
typedef float f32x4 __attribute__((ext_vector_type(4)));

#define LAMBDA_INIT 0.35550906759096928f
#define ONE_MINUS_LI 0.6444909324090307f
#define LOG2E 1.4426950408889634f
// defer-rescale threshold in RAW score units: 8 / (0.125*log2e) ~= 44.36
#define RTHR 44.36f

#if __has_builtin(__builtin_amdgcn_mfma_f32_16x16x16_bf16)
#define MFMA16(a, b, c) __builtin_amdgcn_mfma_f32_16x16x16_bf16(a, b, c, 0, 0, 0)
#elif __has_builtin(__builtin_amdgcn_mfma_f32_16x16x16bf16_1k)
#define MFMA16(a, b, c)                                                       \
  __builtin_amdgcn_mfma_f32_16x16x16bf16_1k(                                  \
      __builtin_bit_cast(s16x4, a), __builtin_bit_cast(s16x4, b), c, 0, 0, 0)
#else
#define MFMA16(a, b, c) (c)  // host pass only — never executed
#endif

// async global->LDS, 16B/lane (gemm only).
#define GLDS(g, l)                                                            \
  __builtin_amdgcn_global_load_lds(                                           \
      (const __attribute__((address_space(1))) void*)(g),                     \
      (__attribute__((address_space(3))) void*)(l), 16, 0, 0)

// ---------------- workspace layout (bytes) ----------------
static const size_t OFF_WCAT = 0;                                  // 6144x1024 bf16
static const size_t OFF_XB = OFF_WCAT + (size_t)6144 * 1024 * 2;   // 4096x1024 bf16
static const size_t OFF_WCT = OFF_XB + (size_t)4096 * 1024 * 2;    // 1024x2048 bf16
static const size_t OFF_PROJ = OFF_WCT + (size_t)2048 * 1024 * 2;  // 4096x6144 bf16
static const size_t OFF_VT = OFF_PROJ + (size_t)4096 * 6144 * 2;   // 64*128*1024 bf16
static const size_t OFF_YLN = OFF_VT + (size_t)64 * 128 * 1024 * 2;// 4096x2048 bf16
static const size_t OFF_LAM = OFF_YLN + (size_t)4096 * 2048 * 2;   // 16 f32

// ---------------- elementwise cast x -> bf16 ----------------
__global__ void __launch_bounds__(256) cast_x(const float* __restrict__ x,
                                              bf16_t* __restrict__ o) {
  const int i = (blockIdx.x * 256 + threadIdx.x) * 4;
  float4 v = *(const float4*)(x + i);
  bf16x4 r = {(bf16_t)v.x, (bf16_t)v.y, (bf16_t)v.z, (bf16_t)v.w};
  *(bf16x4*)(o + i) = r;
}

// ---------------- transpose-cast weight W[K][N] fp32 -> Wt[row0+n][k] bf16 ----
__device__ __forceinline__ void tcast_body(const float* __restrict__ W,
                                           bf16_t* __restrict__ Wt, int K,
                                           int N, int row0) {
  __shared__ float tile[32][33];
  const int k0 = blockIdx.x * 32, n0 = blockIdx.y * 32;
  const int tx = threadIdx.x & 31, ty = threadIdx.x >> 5;  // 32x8
#pragma unroll
  for (int i = 0; i < 32; i += 8)
    tile[ty + i][tx] = W[(long)(k0 + ty + i) * N + n0 + tx];
  __syncthreads();
#pragma unroll
  for (int i = 0; i < 32; i += 8)
    Wt[(long)(row0 + n0 + ty + i) * K + k0 + tx] = (bf16_t)tile[tx][ty + i];
}

__global__ void __launch_bounds__(256) tcast_w(const float* __restrict__ W,
                                               bf16_t* __restrict__ Wt, int K,
                                               int N, int row0) {
  tcast_body(W, Wt, K, N, row0);
}

// fused: the four 1024x1024 q/k weights in one launch (z selects)
__global__ void __launch_bounds__(256) tcast_w4(const float* __restrict__ W0,
                                                const float* __restrict__ W1,
                                                const float* __restrict__ W2,
                                                const float* __restrict__ W3,
                                                bf16_t* __restrict__ Wt) {
  const float* Ws[4] = {W0, W1, W2, W3};
  tcast_body(Ws[blockIdx.z], Wt, 1024, 1024, blockIdx.z * 1024);
}

// ---------------- per-head lambda ----------------
__global__ void lam_kernel(const float* __restrict__ lq1,
                           const float* __restrict__ lk1,
                           const float* __restrict__ lq2,
                           const float* __restrict__ lk2,
                           float* __restrict__ lam) {
  const int h = threadIdx.x;
  if (h < NH) {
    float d1 = 0.f, d2 = 0.f;
    for (int i = 0; i < 64; ++i) {
      d1 += lq1[h * 64 + i] * lk1[h * 64 + i];
      d2 += lq2[h * 64 + i] * lk2[h * 64 + i];
    }
    lam[h] = expf(d1) - expf(d2) + LAMBDA_INIT;
  }
}

// ---------------- GEMM (m97 structure): C[M][N] = A[M][K] @ Bt[N][K]^T -------
#define BM 128
#define BN 128
#define BK 32

template <typename OutT>
__global__ void __launch_bounds__(256) gemm_bt(const bf16_t* __restrict__ A,
                                               const bf16_t* __restrict__ Bt,
                                               OutT* __restrict__ C, int M,
                                               int N, int K) {
  __shared__ __align__(16) bf16_t As[BM * BK];
  __shared__ __align__(16) bf16_t Bs[BN * BK];
  const int tid = threadIdx.x;
  const int w = tid >> 6;
  const int lane = tid & 63;
  const int quad = lane >> 4, l16 = lane & 15;
  const int m0 = blockIdx.y * BM, n0 = blockIdx.x * BN;
  const int wm = (w >> 1) * 64, wn = (w & 1) * 64;
  const int srow = tid >> 2;       // 0..63
  const int scol = (tid & 3) * 8;  // 0,8,16,24

  const bf16_t* Ag0 = A + (long)(m0 + srow) * K + scol;
  const bf16_t* Ag1 = Ag0 + (long)64 * K;
  const bf16_t* Bg0 = Bt + (long)(n0 + srow) * K + scol;
  const bf16_t* Bg1 = Bg0 + (long)64 * K;
  bf16_t* lA0 = As + tid * 8;  // == srow*32 + scol
  bf16_t* lA1 = As + 2048 + tid * 8;
  bf16_t* lB0 = Bs + tid * 8;
  bf16_t* lB1 = Bs + 2048 + tid * 8;

  f32x4 acc[4][4] = {};

  for (int k0 = 0; k0 < K; k0 += BK) {
    GLDS(Ag0 + k0, lA0);
    GLDS(Ag1 + k0, lA1);
    GLDS(Bg0 + k0, lB0);
    GLDS(Bg1 + k0, lB1);
    __syncthreads();
    bf16x8 af[4], bfr[4];
#pragma unroll
    for (int t = 0; t < 4; ++t) {
      af[t] = *(const bf16x8*)(As + (wm + t * 16 + l16) * BK + quad * 8);
      bfr[t] = *(const bf16x8*)(Bs + (wn + t * 16 + l16) * BK + quad * 8);
    }
#pragma unroll
    for (int mt = 0; mt < 4; ++mt)
#pragma unroll
      for (int nt = 0; nt < 4; ++nt)
        acc[mt][nt] = __builtin_amdgcn_mfma_f32_16x16x32_bf16(
            af[mt], bfr[nt], acc[mt][nt], 0, 0, 0);
    __syncthreads();
  }

#pragma unroll
  for (int mt = 0; mt < 4; ++mt)
#pragma unroll
    for (int nt = 0; nt < 4; ++nt) {
      const int col = n0 + wn + nt * 16 + l16;
#pragma unroll
      for (int i = 0; i < 4; ++i) {
        const int row = m0 + wm + mt * 16 + quad * 4 + i;
        C[(long)row * N + col] = (OutT)acc[mt][nt][i];
      }
    }
}

// ---------------- transpose v slice of proj -> vt[(b,h)][d][perm(key)] -------
// Key permutation within each 64-key window (so attn's PV can b128-load two
// 16-key fragment groups at once):  pos(k) = (k&32) | ((k&12)<<1) |
// ((k&16)>>2) | (k&3).  I.e. element j of a b128 at in-window offset
// cp*32+quad*8 is key  cp*32 + (j>>2)*16 + quad*4 + (j&3).
__global__ void __launch_bounds__(256) transpose_v(const bf16_t* __restrict__ proj,
                                                   bf16_t* __restrict__ vt) {
  __shared__ bf16_t tile[32][34];
  const int bh = blockIdx.z;
  const int b = bh >> 4, h = bh & 15;
  const int t0 = blockIdx.x * 32, d0 = blockIdx.y * 32;
  const int tx = threadIdx.x & 31, ty = threadIdx.x >> 5;
  const bf16_t* src = proj + (long)(b * T_SEQ) * NPROJ + 4096 + h * 128;
#pragma unroll
  for (int i = 0; i < 32; i += 8)
    tile[ty + i][tx] = src[(long)(t0 + ty + i) * NPROJ + d0 + tx];
  __syncthreads();
  // write: one 8B chunk per thread.  chunk = 4 keys (s*16+quad*4 .. +3) of
  // one dim row; stored at in-row offset t0 + quad*8 + s*4 (pos-permuted).
  const int d_loc = threadIdx.x >> 3;
  const int g = threadIdx.x & 7;
  const int s = g >> 2, qd = g & 3;
  const int tl = s * 16 + qd * 4;
  bf16x4 o = {tile[tl + 0][d_loc], tile[tl + 1][d_loc], tile[tl + 2][d_loc],
              tile[tl + 3][d_loc]};
  bf16_t* dst = vt + (long)bh * (DV * T_SEQ) + (long)(d0 + d_loc) * T_SEQ;
  *(bf16x4*)(dst + t0 + qd * 8 + s * 4) = o;
}

// ---------------- attention: barrier-free, LDS-free, 1 wave / block ---------
// grid: (4096, 1), 64 threads.  x&7 = XCD (round-robin heuristic); per XCD
// u = x>>3 = p2*128 + qi*8 + bl*4 + w : pair-phase p2 walks the XCD's 8
// (b,h) sets two at a time (~3MB rolling L2 window), qi ascending = qblk
// descending (LPT big-first), w = 16-row q sub-block.
__global__ void __launch_bounds__(64, 3) attn_kernel(const bf16_t* __restrict__ proj,
                                                     const bf16_t* __restrict__ vt,
                                                     const float* __restrict__ lamp,
                                                     bf16_t* __restrict__ yln) {
  const int x = blockIdx.x;
  const int xcd = x & 7;
  const int u = x >> 3;
  const int p2 = u >> 7, r = u & 127;
  const int qi = r >> 3;
  const int bhl = p2 * 2 + ((r >> 2) & 1);
  const int w = r & 3;
  const int qblk = 15 - qi;
  const int bh = (bhl << 3) | xcd;
  const int b = bh >> 4, h = bh & 15;
  const int lane = threadIdx.x;
  const int quad = lane >> 4, l16 = lane & 15;
  const long bT = (long)b * T_SEQ;

  const float sc = 0.125f * LOG2E;  // 1/sqrt(64) folded with log2(e)
  const float lam = lamp[h];
  const int q0 = qblk * 64 + w * 16;
  const int qg = q0 + l16;  // this lane's q row (all fragments)

  // ---- Q fragments (B-operand role) ----
  const bf16_t* qrow = proj + (bT + qg) * (long)NPROJ + h * 64;
  bf16x8 aq1[2], aq2[2];
  aq1[0] = *(const bf16x8*)(qrow + quad * 8);
  aq1[1] = *(const bf16x8*)(qrow + 32 + quad * 8);
  aq2[0] = *(const bf16x8*)(qrow + 1024 + quad * 8);
  aq2[1] = *(const bf16x8*)(qrow + 1024 + 32 + quad * 8);

  // K base: row (bT + kt + c*16 + l16), col h*64+2048 + quad*8 (+32 / +1024)
  const bf16_t* kb = proj + (bT + l16) * (long)NPROJ + h * 64 + 2048 + quad * 8;
  // V base: permuted vt row (f*16+l16), in-row (kt + cp*32 + quad*8)
  const bf16_t* vb = vt + (long)bh * (DV * T_SEQ) + (long)l16 * T_SEQ + quad * 8;

  f32x4 O1[8] = {}, O2[8] = {};  // O^T[d=f*16+quad*4+reg][q=l16]
  float m1 = -3.0e38f, m2 = -3.0e38f, l1 = 0.f, l2 = 0.f;
  const bf16x4 one4 = {(bf16_t)1.0f, (bf16_t)1.0f, (bf16_t)1.0f, (bf16_t)1.0f};

  const int kend = q0 + 16;
  for (int kt = 0; kt < kend; kt += 64) {
    // ---- S^T = K Q^T : A=K-frag (global, L2-hit), B=Q-frag (regs) ----
    f32x4 s1[4], s2[4];
#pragma unroll
    for (int c = 0; c < 4; ++c) {
      const bf16_t* kp = kb + (long)(kt + c * 16) * NPROJ;
      bf16x8 ka0 = *(const bf16x8*)(kp);
      bf16x8 ka1 = *(const bf16x8*)(kp + 32);
      bf16x8 kb0 = *(const bf16x8*)(kp + 1024);
      bf16x8 kb1 = *(const bf16x8*)(kp + 1056);
      f32x4 z = {};
      z = __builtin_amdgcn_mfma_f32_16x16x32_bf16(ka0, aq1[0], z, 0, 0, 0);
      z = __builtin_amdgcn_mfma_f32_16x16x32_bf16(ka1, aq1[1], z, 0, 0, 0);
      s1[c] = z;
      f32x4 z2 = {};
      z2 = __builtin_amdgcn_mfma_f32_16x16x32_bf16(kb0, aq2[0], z2, 0, 0, 0);
      z2 = __builtin_amdgcn_mfma_f32_16x16x32_bf16(kb1, aq2[1], z2, 0, 0, 0);
      s2[c] = z2;
    }
    // ---- causal mask on RAW scores + in-lane TREE max ----
    const bool need_mask = (kt + 63 > q0);
    if (need_mask) {
#pragma unroll
      for (int c = 0; c < 4; ++c)
#pragma unroll
        for (int i = 0; i < 4; ++i) {
          const int key = kt + c * 16 + quad * 4 + i;
          if (key > qg) {
            s1[c][i] = -1e30f;
            s2[c][i] = -1e30f;
          }
        }
    }
    float t1[4], t2[4];
#pragma unroll
    for (int c = 0; c < 4; ++c) {
      t1[c] = fmaxf(fmaxf(s1[c][0], s1[c][1]), fmaxf(s1[c][2], s1[c][3]));
      t2[c] = fmaxf(fmaxf(s2[c][0], s2[c][1]), fmaxf(s2[c][2], s2[c][3]));
    }
    float mx1 = fmaxf(fmaxf(t1[0], t1[1]), fmaxf(t1[2], t1[3]));
    float mx2 = fmaxf(fmaxf(t2[0], t2[1]), fmaxf(t2[2], t2[3]));
    mx1 = fmaxf(mx1, __shfl_xor(mx1, 16));
    mx1 = fmaxf(mx1, __shfl_xor(mx1, 32));
    mx2 = fmaxf(mx2, __shfl_xor(mx2, 16));
    mx2 = fmaxf(mx2, __shfl_xor(mx2, 32));
    // ---- defer-rescale (T13) ----
    if (!__all((mx1 <= m1 + RTHR) && (mx2 <= m2 + RTHR))) {
      const float mn1 = fmaxf(m1, mx1), mn2 = fmaxf(m2, mx2);
      const float al1 = exp2f((m1 - mn1) * sc);
      const float al2 = exp2f((m2 - mn2) * sc);
      m1 = mn1;
      m2 = mn2;
#pragma unroll
      for (int f = 0; f < 8; ++f)
#pragma unroll
        for (int i = 0; i < 4; ++i) {
          O1[f][i] *= al1;
          O2[f][i] *= al2;
        }
      l1 *= al1;
      l2 *= al2;
    }
    // ---- P = exp2(fma(s,sc,-m*sc)), packed bf16x4 per c ----
    const float ms1 = m1 * sc, ms2 = m2 * sc;
    bf16x4 pc1[4], pc2[4];
#pragma unroll
    for (int c = 0; c < 4; ++c)
#pragma unroll
      for (int i = 0; i < 4; ++i) {
        pc1[c][i] = (bf16_t)exp2f(fmaf(s1[c][i], sc, -ms1));
        pc2[c][i] = (bf16_t)exp2f(fmaf(s2[c][i], sc, -ms2));
      }
    // ---- row-sum l via ones-row MFMA ----
    f32x4 la1 = {}, la2 = {};
#pragma unroll
    for (int c = 0; c < 4; ++c) {
      la1 = MFMA16(one4, pc1[c], la1);
      la2 = MFMA16(one4, pc2[c], la2);
    }
    // ---- PV: O^T += V^T P^T, V frags b128 direct from permuted vt ----
#pragma unroll
    for (int cp = 0; cp < 2; ++cp) {
      const bf16_t* vp = vb + kt + cp * 32;
#pragma unroll
      for (int f = 0; f < 8; ++f) {
        bf16x8 va = *(const bf16x8*)(vp + (long)f * 16 * T_SEQ);
        bf16x4 lo = __builtin_shufflevector(va, va, 0, 1, 2, 3);
        bf16x4 hi = __builtin_shufflevector(va, va, 4, 5, 6, 7);
        O1[f] = MFMA16(lo, pc1[2 * cp], O1[f]);
        O2[f] = MFMA16(lo, pc2[2 * cp], O2[f]);
        O1[f] = MFMA16(hi, pc1[2 * cp + 1], O1[f]);
        O2[f] = MFMA16(hi, pc2[2 * cp + 1], O2[f]);
      }
    }
    l1 += la1[0];
    l2 += la2[0];
  }

  // ---- combine streams, subLN over 128 dims, scale, store bf16 ----
  const float inv1 = 1.0f / l1, inv2 = lam / l2;
  float sm = 0.f, sq = 0.f;
#pragma unroll
  for (int f = 0; f < 8; ++f)
#pragma unroll
    for (int i = 0; i < 4; ++i) {
      float y = O1[f][i] * inv1 - O2[f][i] * inv2;
      O1[f][i] = y;
      sm += y;
      sq += y * y;
    }
  sm += __shfl_xor(sm, 16);
  sm += __shfl_xor(sm, 32);
  sq += __shfl_xor(sq, 16);
  sq += __shfl_xor(sq, 32);
  const float mu = sm * (1.0f / 128.0f);
  const float var = sq * (1.0f / 128.0f) - mu * mu;
  const float rs = rsqrtf(var + 1e-5f) * ONE_MINUS_LI;
  bf16_t* dst = yln + (bT + qg) * (long)2048 + h * 128 + quad * 4;
#pragma unroll
  for (int f = 0; f < 8; ++f) {
    bf16x4 o = {(bf16_t)((O1[f][0] - mu) * rs), (bf16_t)((O1[f][1] - mu) * rs),
                (bf16_t)((O1[f][2] - mu) * rs), (bf16_t)((O1[f][3] - mu) * rs)};
    *(bf16x4*)(dst + f * 16) = o;
  }
}

// ---------------------------------------------------------------------------
extern "C" void kernel_launch(void* const* d_in, const int* in_sizes, int n_in,
                              void* d_out, int out_size, void* d_ws,
                              size_t ws_size, hipStream_t stream) {
  const float* x = (const float*)d_in[0];
  const float* Wq1 = (const float*)d_in[1];
  const float* Wq2 = (const float*)d_in[2];
  const float* Wk1 = (const float*)d_in[3];
  const float* Wk2 = (const float*)d_in[4];
  const float* Wv = (const float*)d_in[5];
  const float* Wc = (const float*)d_in[6];
  const float* lq1 = (const float*)d_in[7];
  const float* lk1 = (const float*)d_in[8];
  const float* lq2 = (const float*)d_in[9];
  const float* lk2 = (const float*)d_in[10];
  float* out = (float*)d_out;

  char* ws = (char*)d_ws;
  bf16_t* wcat = (bf16_t*)(ws + OFF_WCAT);
  bf16_t* xb = (bf16_t*)(ws + OFF_XB);
  bf16_t* wct = (bf16_t*)(ws + OFF_WCT);
  bf16_t* projb = (bf16_t*)(ws + OFF_PROJ);
  bf16_t* vtb = (bf16_t*)(ws + OFF_VT);
  bf16_t* ylnb = (bf16_t*)(ws + OFF_YLN);
  float* lamp = (float*)(ws + OFF_LAM);

  cast_x<<<4096, 256, 0, stream>>>(x, xb);
  tcast_w4<<<dim3(32, 32, 4), 256, 0, stream>>>(Wq1, Wq2, Wk1, Wk2, wcat);
  tcast_w<<<dim3(32, 64), 256, 0, stream>>>(Wv, wcat, 1024, 2048, 4096);
  tcast_w<<<dim3(64, 32), 256, 0, stream>>>(Wc, wct, 2048, 1024, 0);
  lam_kernel<<<1, 64, 0, stream>>>(lq1, lk1, lq2, lk2, lamp);

  // proj = xb @ wcat^T : M=4096 N=6144 K=1024
  gemm_bt<bf16_t><<<dim3(48, 32), 256, 0, stream>>>(xb, wcat, projb, 4096, 6144, 1024);
  transpose_v<<<dim3(32, 4, 64), 256, 0, stream>>>(projb, vtb);
  attn_kernel<<<dim3(4096), 64, 0, stream>>>(projb, vtb, lamp, ylnb);
  // out = yln @ wc^T : M=4096 N=1024 K=2048
  gemm_bt<float><<<dim3(8, 32), 256, 0, stream>>>(ylnb, wct, out, 4096, 1024, 2048);
}

// Round 3
// 308.560 us; speedup vs baseline: 1.2866x; 1.2866x over previous
//
#include <hip/hip_runtime.h>

// ---------------------------------------------------------------------------
// DiffAttention forward, bf16 MFMA pipeline.  B=4 T=1024 C=1024 H=16 hs=64 dv=128.
//   1. cast x -> bf16; transpose-cast weights -> W^T[n][k] bf16
//   2. proj GEMM (m97-style global_load_lds): proj[4096][6144] = xb @ wcat^T
//   3. transpose v slice -> vt[(b,h)][dim][token]  (plain layout)
//   4. attention, SPLIT-STREAM: each 256-thr block computes ONE score stream
//      (own K, shared V) for one qblk with the R1 pipeline: reg-prefetch ->
//      LDS staging, S^T = K Q^T (16x16x32), in-lane tree max + 2 shfl,
//      defer-rescale (T13), P bf16, row-sum l via ones-row MFMA, PV
//      O^T += V^T P^T (16x16x16). Writes normalized per-stream a_s = (P/l)V
//      as fp16. Rationale: R1's VGPR+AGPR state (~240) capped real occupancy
//      at ~1 block/CU (Occupancy 10.6%); halving per-wave state doubles+ it.
//   4b. combine: y = a1 - lam_h*a2, subLN over 128, *(1-LI), bf16 -> yln.
//      IN PLACE: a1 lives in the yln region; a2 in the dead wcat/xb region.
//   5. out GEMM: out[4096][1024] fp32 = yln @ wc^T  (BN=64 tiles, 512 blocks)
// MFMA mappings (HW-verified): A[m=lane&15][k=quad*8+j] (K=32) / quad*4+j
// (K=16); B^T[n=lane&15][k=same]; C/D: col=lane&15, row=quad*4+reg.
// R8 lesson: #else of the MFMA16 guard must be host-safe.
// R9 lesson: attn LDS bank conflicts are the b64/b128 aliasing floor.
// R10 lesson (R2 post-mortem): no-LDS direct-global attn REGRESSED 104->166
// (latency exposed every tile, 4x redundant loads). Keep LDS staging.
// ---------------------------------------------------------------------------

#define T_SEQ 1024
#define NH 16
#define DV 128
#define NPROJ 6144
#define KSTR 72  // K/V LDS row stride (elements)

typedef __bf16 bf16_t;
typedef __bf16 bf16x8 __attribute__((ext_vector_type(8)));
typedef __bf16 bf16x4 __attribute__((ext_vector_type(4)));
typedef __bf16 bf16x2 __attribute__((ext_vector_type(2)));
typedef _Float16 f16x4 __attribute__((ext_vector_type(4)));
typedef _Float16 f16x2 __attribute__((ext_vector_type(2)));
typedef short s16x4 __attribute__((ext_vector_type(4)));
typedef float f32x4 __attribute__((ext_vector_type(4)));

#define LAMBDA_INIT 0.35550906759096928f
#define ONE_MINUS_LI 0.6444909324090307f
#define LOG2E 1.4426950408889634f
// defer-rescale threshold in RAW score units: 8 / (0.125*log2e) ~= 44.36
#define RTHR 44.36f

#if __has_builtin(__builtin_amdgcn_mfma_f32_16x16x16_bf16)
#define MFMA16(a, b, c) __builtin_amdgcn_mfma_f32_16x16x16_bf16(a, b, c, 0, 0, 0)
#elif __has_builtin(__builtin_amdgcn_mfma_f32_16x16x16bf16_1k)
#define MFMA16(a, b, c)                                                       \
  __builtin_amdgcn_mfma_f32_16x16x16bf16_1k(                                  \
      __builtin_bit_cast(s16x4, a), __builtin_bit_cast(s16x4, b), c, 0, 0, 0)
#else
#define MFMA16(a, b, c) (c)  // host pass only — never executed
#endif

// async global->LDS, 16B/lane (gemm only).
#define GLDS(g, l)                                                            \
  __builtin_amdgcn_global_load_lds(                                           \
      (const __attribute__((address_space(1))) void*)(g),                     \
      (__attribute__((address_space(3))) void*)(l), 16, 0, 0)

// ---------------- workspace layout (bytes) ----------------
static const size_t OFF_WCAT = 0;                                  // 6144x1024 bf16
static const size_t OFF_XB = OFF_WCAT + (size_t)6144 * 1024 * 2;   // 4096x1024 bf16
static const size_t OFF_WCT = OFF_XB + (size_t)4096 * 1024 * 2;    // 1024x2048 bf16
static const size_t OFF_PROJ = OFF_WCT + (size_t)2048 * 1024 * 2;  // 4096x6144 bf16
static const size_t OFF_VT = OFF_PROJ + (size_t)4096 * 6144 * 2;   // 64*128*1024 bf16
static const size_t OFF_YLN = OFF_VT + (size_t)64 * 128 * 1024 * 2;// 4096x2048 bf16
static const size_t OFF_LAM = OFF_YLN + (size_t)4096 * 2048 * 2;   // 16 f32
// a1 (fp16, 4096*16*128 = 16.78 MB) aliases the YLN region (combine rewrites
// it in place).  a2 (same size) aliases WCAT+XB (dead after proj GEMM).

// ---------------- elementwise cast x -> bf16 ----------------
__global__ void __launch_bounds__(256) cast_x(const float* __restrict__ x,
                                              bf16_t* __restrict__ o) {
  const int i = (blockIdx.x * 256 + threadIdx.x) * 4;
  float4 v = *(const float4*)(x + i);
  bf16x4 r = {(bf16_t)v.x, (bf16_t)v.y, (bf16_t)v.z, (bf16_t)v.w};
  *(bf16x4*)(o + i) = r;
}

// ---------------- transpose-cast weight W[K][N] fp32 -> Wt[row0+n][k] bf16 ----
__device__ __forceinline__ void tcast_body(const float* __restrict__ W,
                                           bf16_t* __restrict__ Wt, int K,
                                           int N, int row0) {
  __shared__ float tile[32][33];
  const int k0 = blockIdx.x * 32, n0 = blockIdx.y * 32;
  const int tx = threadIdx.x & 31, ty = threadIdx.x >> 5;  // 32x8
#pragma unroll
  for (int i = 0; i < 32; i += 8)
    tile[ty + i][tx] = W[(long)(k0 + ty + i) * N + n0 + tx];
  __syncthreads();
#pragma unroll
  for (int i = 0; i < 32; i += 8)
    Wt[(long)(row0 + n0 + ty + i) * K + k0 + tx] = (bf16_t)tile[tx][ty + i];
}

__global__ void __launch_bounds__(256) tcast_w(const float* __restrict__ W,
                                               bf16_t* __restrict__ Wt, int K,
                                               int N, int row0) {
  tcast_body(W, Wt, K, N, row0);
}

// fused: the four 1024x1024 q/k weights in one launch (z selects)
__global__ void __launch_bounds__(256) tcast_w4(const float* __restrict__ W0,
                                                const float* __restrict__ W1,
                                                const float* __restrict__ W2,
                                                const float* __restrict__ W3,
                                                bf16_t* __restrict__ Wt) {
  const float* Ws[4] = {W0, W1, W2, W3};
  tcast_body(Ws[blockIdx.z], Wt, 1024, 1024, blockIdx.z * 1024);
}

// ---------------- per-head lambda ----------------
__global__ void lam_kernel(const float* __restrict__ lq1,
                           const float* __restrict__ lk1,
                           const float* __restrict__ lq2,
                           const float* __restrict__ lk2,
                           float* __restrict__ lam) {
  const int h = threadIdx.x;
  if (h < NH) {
    float d1 = 0.f, d2 = 0.f;
    for (int i = 0; i < 64; ++i) {
      d1 += lq1[h * 64 + i] * lk1[h * 64 + i];
      d2 += lq2[h * 64 + i] * lk2[h * 64 + i];
    }
    lam[h] = expf(d1) - expf(d2) + LAMBDA_INIT;
  }
}

// ---------------- GEMM (m97 structure): C[M][N] = A[M][K] @ Bt[N][K]^T -------
#define BM 128
#define BN 128
#define BK 32

template <typename OutT>
__global__ void __launch_bounds__(256) gemm_bt(const bf16_t* __restrict__ A,
                                               const bf16_t* __restrict__ Bt,
                                               OutT* __restrict__ C, int M,
                                               int N, int K) {
  __shared__ __align__(16) bf16_t As[BM * BK];
  __shared__ __align__(16) bf16_t Bs[BN * BK];
  const int tid = threadIdx.x;
  const int w = tid >> 6;
  const int lane = tid & 63;
  const int quad = lane >> 4, l16 = lane & 15;
  const int m0 = blockIdx.y * BM, n0 = blockIdx.x * BN;
  const int wm = (w >> 1) * 64, wn = (w & 1) * 64;
  const int srow = tid >> 2;       // 0..63
  const int scol = (tid & 3) * 8;  // 0,8,16,24

  const bf16_t* Ag0 = A + (long)(m0 + srow) * K + scol;
  const bf16_t* Ag1 = Ag0 + (long)64 * K;
  const bf16_t* Bg0 = Bt + (long)(n0 + srow) * K + scol;
  const bf16_t* Bg1 = Bg0 + (long)64 * K;
  bf16_t* lA0 = As + tid * 8;  // == srow*32 + scol
  bf16_t* lA1 = As + 2048 + tid * 8;
  bf16_t* lB0 = Bs + tid * 8;
  bf16_t* lB1 = Bs + 2048 + tid * 8;

  f32x4 acc[4][4] = {};

  for (int k0 = 0; k0 < K; k0 += BK) {
    GLDS(Ag0 + k0, lA0);
    GLDS(Ag1 + k0, lA1);
    GLDS(Bg0 + k0, lB0);
    GLDS(Bg1 + k0, lB1);
    __syncthreads();
    bf16x8 af[4], bfr[4];
#pragma unroll
    for (int t = 0; t < 4; ++t) {
      af[t] = *(const bf16x8*)(As + (wm + t * 16 + l16) * BK + quad * 8);
      bfr[t] = *(const bf16x8*)(Bs + (wn + t * 16 + l16) * BK + quad * 8);
    }
#pragma unroll
    for (int mt = 0; mt < 4; ++mt)
#pragma unroll
      for (int nt = 0; nt < 4; ++nt)
        acc[mt][nt] = __builtin_amdgcn_mfma_f32_16x16x32_bf16(
            af[mt], bfr[nt], acc[mt][nt], 0, 0, 0);
    __syncthreads();
  }

#pragma unroll
  for (int mt = 0; mt < 4; ++mt)
#pragma unroll
    for (int nt = 0; nt < 4; ++nt) {
      const int col = n0 + wn + nt * 16 + l16;
#pragma unroll
      for (int i = 0; i < 4; ++i) {
        const int row = m0 + wm + mt * 16 + quad * 4 + i;
        C[(long)row * N + col] = (OutT)acc[mt][nt][i];
      }
    }
}

// ---------------- GEMM, BN=64 variant (for out: M=4096 N=1024 -> 512 blocks) --
template <typename OutT>
__global__ void __launch_bounds__(256) gemm_bt_n64(const bf16_t* __restrict__ A,
                                                   const bf16_t* __restrict__ Bt,
                                                   OutT* __restrict__ C, int M,
                                                   int N, int K) {
  __shared__ __align__(16) bf16_t As[BM * BK];
  __shared__ __align__(16) bf16_t Bs[64 * BK];
  const int tid = threadIdx.x;
  const int w = tid >> 6;
  const int lane = tid & 63;
  const int quad = lane >> 4, l16 = lane & 15;
  const int m0 = blockIdx.y * BM, n0 = blockIdx.x * 64;
  const int wm = (w >> 1) * 64, wn = (w & 1) * 32;
  const int srow = tid >> 2;       // 0..63
  const int scol = (tid & 3) * 8;  // 0,8,16,24

  const bf16_t* Ag0 = A + (long)(m0 + srow) * K + scol;
  const bf16_t* Ag1 = Ag0 + (long)64 * K;
  const bf16_t* Bg0 = Bt + (long)(n0 + srow) * K + scol;
  bf16_t* lA0 = As + tid * 8;
  bf16_t* lA1 = As + 2048 + tid * 8;
  bf16_t* lB0 = Bs + tid * 8;

  f32x4 acc[4][2] = {};

  for (int k0 = 0; k0 < K; k0 += BK) {
    GLDS(Ag0 + k0, lA0);
    GLDS(Ag1 + k0, lA1);
    GLDS(Bg0 + k0, lB0);
    __syncthreads();
    bf16x8 af[4], bfr[2];
#pragma unroll
    for (int t = 0; t < 4; ++t)
      af[t] = *(const bf16x8*)(As + (wm + t * 16 + l16) * BK + quad * 8);
#pragma unroll
    for (int t = 0; t < 2; ++t)
      bfr[t] = *(const bf16x8*)(Bs + (wn + t * 16 + l16) * BK + quad * 8);
#pragma unroll
    for (int mt = 0; mt < 4; ++mt)
#pragma unroll
      for (int nt = 0; nt < 2; ++nt)
        acc[mt][nt] = __builtin_amdgcn_mfma_f32_16x16x32_bf16(
            af[mt], bfr[nt], acc[mt][nt], 0, 0, 0);
    __syncthreads();
  }

#pragma unroll
  for (int mt = 0; mt < 4; ++mt)
#pragma unroll
    for (int nt = 0; nt < 2; ++nt) {
      const int col = n0 + wn + nt * 16 + l16;
#pragma unroll
      for (int i = 0; i < 4; ++i) {
        const int row = m0 + wm + mt * 16 + quad * 4 + i;
        C[(long)row * N + col] = (OutT)acc[mt][nt][i];
      }
    }
}

// ---------------- transpose v slice of proj -> vt[(b,h)][d][t] (plain) -------
__global__ void __launch_bounds__(256) transpose_v(const bf16_t* __restrict__ proj,
                                                   bf16_t* __restrict__ vt) {
  __shared__ bf16_t tile[32][34];
  const int bh = blockIdx.z;
  const int b = bh >> 4, h = bh & 15;
  const int t0 = blockIdx.x * 32, d0 = blockIdx.y * 32;
  const int tx = threadIdx.x & 31, ty = threadIdx.x >> 5;
  const bf16_t* src = proj + (long)(b * T_SEQ) * NPROJ + 4096 + h * 128;
#pragma unroll
  for (int i = 0; i < 32; i += 8)
    tile[ty + i][tx] = src[(long)(t0 + ty + i) * NPROJ + d0 + tx];
  __syncthreads();
  bf16_t* dst = vt + ((long)bh * DV) * T_SEQ;
#pragma unroll
  for (int i = 0; i < 32; i += 8)
    dst[(long)(d0 + ty + i) * T_SEQ + t0 + tx] = tile[tx][ty + i];
}

// ---------------- attention: split-stream, one (qblk, stream) per block ------
// grid: (2048). x>>7 = qi (qblk = 15-qi, big first / LPT), st = (x>>6)&1,
// bh = x&63 (x%8 tracks bh -> same-(b,h) blocks share an XCD's L2).
// 4 waves; wave w owns q rows q0..q0+15 (q = lane&15 for all fragments).
__global__ void __launch_bounds__(256) attn_kernel(const bf16_t* __restrict__ proj,
                                                   const bf16_t* __restrict__ vt,
                                                   _Float16* __restrict__ a1,
                                                   _Float16* __restrict__ a2) {
  const int x = blockIdx.x;
  const int qblk = 15 - (x >> 7);
  const int st = (x >> 6) & 1;
  const int bh = x & 63;
  const int b = bh >> 4, h = bh & 15;
  const int tid = threadIdx.x;
  const int w = tid >> 6, lane = tid & 63;
  const int quad = lane >> 4, l16 = lane & 15;
  const long bT = (long)b * T_SEQ;

  __shared__ __align__(16) bf16_t Ks[64 * KSTR];  // [key][dim]
  __shared__ __align__(16) bf16_t Vs[DV * KSTR];  // [dim][key]

  // ---- staging source pointers (this stream's K; shared V) ----
  const int koff = h * 64 + 2048 + st * 1024;
  const bf16_t* gK = proj + (bT + (tid >> 2)) * (long)NPROJ + koff + (tid & 3) * 16;
  const bf16_t* gV = vt + (long)bh * DV * T_SEQ + (long)(tid >> 1) * T_SEQ +
                     (tid & 1) * 32;
  const int kwK = (tid >> 2) * KSTR + (tid & 3) * 16;
  const int kwV = (tid >> 1) * KSTR + (tid & 1) * 32;

  const float sc = 0.125f * LOG2E;  // 1/sqrt(64) folded with log2(e)
  const int q0 = qblk * 64 + w * 16;
  const int qg = q0 + l16;  // this lane's q row (all fragments)

  // ---- Q fragments (B-operand role), this stream only ----
  const bf16_t* qrow = proj + (bT + qg) * (long)NPROJ + h * 64 + st * 1024;
  bf16x8 aq[2];
  aq[0] = *(const bf16x8*)(qrow + quad * 8);
  aq[1] = *(const bf16x8*)(qrow + 32 + quad * 8);

  f32x4 O[8] = {};  // O^T[d=f*16+quad*4+reg][q=l16]
  float m = -3.0e38f, l = 0.f;
  const bf16x4 one4 = {(bf16_t)1.0f, (bf16_t)1.0f, (bf16_t)1.0f, (bf16_t)1.0f};

  const int kend_blk = qblk * 64 + 64;
  const int kend_w = q0 + 16;

  // ---- prime the register pipeline with tile kt=0 ----
  bf16x8 rK[2], rV[4];
  rK[0] = *(const bf16x8*)(gK);
  rK[1] = *(const bf16x8*)(gK + 8);
#pragma unroll
  for (int j = 0; j < 4; ++j) rV[j] = *(const bf16x8*)(gV + j * 8);

  for (int kt = 0; kt < kend_blk; kt += 64) {
    // ---- commit staged registers to LDS ----
    *(bf16x8*)(Ks + kwK) = rK[0];
    *(bf16x8*)(Ks + kwK + 8) = rK[1];
#pragma unroll
    for (int j = 0; j < 4; ++j) *(bf16x8*)(Vs + kwV + j * 8) = rV[j];
    __syncthreads();

    // ---- prefetch next tile into registers (overlaps compute) ----
    if (kt + 64 < kend_blk) {
      const long ko = (long)(kt + 64) * NPROJ;
      rK[0] = *(const bf16x8*)(gK + ko);
      rK[1] = *(const bf16x8*)(gK + ko + 8);
#pragma unroll
      for (int j = 0; j < 4; ++j)
        rV[j] = *(const bf16x8*)(gV + kt + 64 + j * 8);
    }

    if (kt < kend_w) {
      // ---- S^T = K Q^T : A=K-frag (from LDS), B=Q-frag (regs) ----
      f32x4 s[4];
#pragma unroll
      for (int c = 0; c < 4; ++c) {
        const bf16_t* kr = Ks + (c * 16 + l16) * KSTR;
        bf16x8 ka0 = *(const bf16x8*)(kr + quad * 8);
        bf16x8 ka1 = *(const bf16x8*)(kr + 32 + quad * 8);
        f32x4 z = {};
        z = __builtin_amdgcn_mfma_f32_16x16x32_bf16(ka0, aq[0], z, 0, 0, 0);
        z = __builtin_amdgcn_mfma_f32_16x16x32_bf16(ka1, aq[1], z, 0, 0, 0);
        s[c] = z;
      }
      // ---- causal mask (diagonal tile only) + in-lane TREE max ----
      if (kt + 63 > q0) {
#pragma unroll
        for (int c = 0; c < 4; ++c)
#pragma unroll
          for (int i = 0; i < 4; ++i) {
            const int key = kt + c * 16 + quad * 4 + i;
            if (key > qg) s[c][i] = -1e30f;
          }
      }
      float t[4];
#pragma unroll
      for (int c = 0; c < 4; ++c)
        t[c] = fmaxf(fmaxf(s[c][0], s[c][1]), fmaxf(s[c][2], s[c][3]));
      float mx = fmaxf(fmaxf(t[0], t[1]), fmaxf(t[2], t[3]));
      mx = fmaxf(mx, __shfl_xor(mx, 16));
      mx = fmaxf(mx, __shfl_xor(mx, 32));
      // ---- defer-rescale (T13) ----
      if (!__all(mx <= m + RTHR)) {
        const float mn = fmaxf(m, mx);
        const float al = exp2f((m - mn) * sc);
        m = mn;
#pragma unroll
        for (int f = 0; f < 8; ++f)
#pragma unroll
          for (int i = 0; i < 4; ++i) O[f][i] *= al;
        l *= al;
      }
      // ---- P = exp2(fma(s,sc,-m*sc)), packed bf16x4 per c ----
      const float ms = m * sc;
      bf16x4 pc[4];
#pragma unroll
      for (int c = 0; c < 4; ++c)
#pragma unroll
        for (int i = 0; i < 4; ++i)
          pc[c][i] = (bf16_t)exp2f(fmaf(s[c][i], sc, -ms));
      // ---- row-sum l via ones-row MFMA ----
      f32x4 la = {};
#pragma unroll
      for (int c = 0; c < 4; ++c) la = MFMA16(one4, pc[c], la);
      // ---- PV: O^T += V^T P^T ----
#pragma unroll
      for (int c = 0; c < 4; ++c) {
#pragma unroll
        for (int f = 0; f < 8; ++f) {
          bf16x4 va =
              *(const bf16x4*)(Vs + (f * 16 + l16) * KSTR + c * 16 + quad * 4);
          O[f] = MFMA16(va, pc[c], O[f]);
        }
      }
      l += la[0];
    }
    __syncthreads();
  }

  // ---- normalize and store per-stream a_s = (P/l)V as fp16 ----
  const float inv = 1.0f / l;
  _Float16* ob = st ? a2 : a1;
  _Float16* dst = ob + ((bT + qg) * 16 + h) * (long)128 + quad * 4;
#pragma unroll
  for (int f = 0; f < 8; ++f) {
    f16x4 o = {(_Float16)(O[f][0] * inv), (_Float16)(O[f][1] * inv),
               (_Float16)(O[f][2] * inv), (_Float16)(O[f][3] * inv)};
    *(f16x4*)(dst + f * 16) = o;
  }
}

// ---------------- combine: y = a1 - lam*a2, subLN(128), *(1-LI) -> bf16 ------
// One wave per (token,head) unit; lane holds 2 dims. IN PLACE over a1 (= yln
// region): every lane reads its 4B before the wave's reduction, then writes.
__global__ void __launch_bounds__(256) combine_kernel(const _Float16* __restrict__ a1,
                                                      const _Float16* __restrict__ a2,
                                                      const float* __restrict__ lamp,
                                                      bf16_t* __restrict__ yln) {
  const int unit = blockIdx.x * 4 + (threadIdx.x >> 6);  // 0..65535 = r*16+h
  const int lane = threadIdx.x & 63;
  const float lam = lamp[unit & 15];
  const long base = (long)unit * 128 + lane * 2;
  f16x2 v1 = *(const f16x2*)(a1 + base);
  f16x2 v2 = *(const f16x2*)(a2 + base);
  float y0 = (float)v1[0] - lam * (float)v2[0];
  float y1 = (float)v1[1] - lam * (float)v2[1];
  float sm = y0 + y1, sq = y0 * y0 + y1 * y1;
#pragma unroll
  for (int off = 1; off < 64; off <<= 1) {
    sm += __shfl_xor(sm, off);
    sq += __shfl_xor(sq, off);
  }
  const float mu = sm * (1.0f / 128.0f);
  const float var = sq * (1.0f / 128.0f) - mu * mu;
  const float rs = rsqrtf(var + 1e-5f) * ONE_MINUS_LI;
  bf16x2 o = {(bf16_t)((y0 - mu) * rs), (bf16_t)((y1 - mu) * rs)};
  *(bf16x2*)(yln + base) = o;
}

// ---------------------------------------------------------------------------
extern "C" void kernel_launch(void* const* d_in, const int* in_sizes, int n_in,
                              void* d_out, int out_size, void* d_ws,
                              size_t ws_size, hipStream_t stream) {
  const float* x = (const float*)d_in[0];
  const float* Wq1 = (const float*)d_in[1];
  const float* Wq2 = (const float*)d_in[2];
  const float* Wk1 = (const float*)d_in[3];
  const float* Wk2 = (const float*)d_in[4];
  const float* Wv = (const float*)d_in[5];
  const float* Wc = (const float*)d_in[6];
  const float* lq1 = (const float*)d_in[7];
  const float* lk1 = (const float*)d_in[8];
  const float* lq2 = (const float*)d_in[9];
  const float* lk2 = (const float*)d_in[10];
  float* out = (float*)d_out;

  char* ws = (char*)d_ws;
  bf16_t* wcat = (bf16_t*)(ws + OFF_WCAT);
  bf16_t* xb = (bf16_t*)(ws + OFF_XB);
  bf16_t* wct = (bf16_t*)(ws + OFF_WCT);
  bf16_t* projb = (bf16_t*)(ws + OFF_PROJ);
  bf16_t* vtb = (bf16_t*)(ws + OFF_VT);
  bf16_t* ylnb = (bf16_t*)(ws + OFF_YLN);
  float* lamp = (float*)(ws + OFF_LAM);
  _Float16* a1b = (_Float16*)(ws + OFF_YLN);   // aliases yln (in-place combine)
  _Float16* a2b = (_Float16*)(ws + OFF_WCAT);  // aliases wcat+xb (dead after proj)

  cast_x<<<4096, 256, 0, stream>>>(x, xb);
  tcast_w4<<<dim3(32, 32, 4), 256, 0, stream>>>(Wq1, Wq2, Wk1, Wk2, wcat);
  tcast_w<<<dim3(32, 64), 256, 0, stream>>>(Wv, wcat, 1024, 2048, 4096);
  tcast_w<<<dim3(64, 32), 256, 0, stream>>>(Wc, wct, 2048, 1024, 0);
  lam_kernel<<<1, 64, 0, stream>>>(lq1, lk1, lq2, lk2, lamp);

  // proj = xb @ wcat^T : M=4096 N=6144 K=1024
  gemm_bt<bf16_t><<<dim3(48, 32), 256, 0, stream>>>(xb, wcat, projb, 4096, 6144, 1024);
  transpose_v<<<dim3(32, 4, 64), 256, 0, stream>>>(projb, vtb);
  attn_kernel<<<dim3(2048), 256, 0, stream>>>(projb, vtb, a1b, a2b);
  combine_kernel<<<dim3(16384), 256, 0, stream>>>(a1b, a2b, lamp, ylnb);
  // out = yln @ wc^T : M=4096 N=1024 K=2048  (BN=64 -> 512 blocks)
  gemm_bt_n64<float><<<dim3(16, 32), 256, 0, stream>>>(ylnb, wct, out, 4096, 1024, 2048);
}

// Round 4
// 305.926 us; speedup vs baseline: 1.2977x; 1.0086x over previous
//
#include <hip/hip_runtime.h>

// ---------------------------------------------------------------------------
// DiffAttention forward, bf16 MFMA pipeline.  B=4 T=1024 C=1024 H=16 hs=64 dv=128.
//   1. cast x -> bf16; transpose-cast weights -> W^T[n][k] bf16
//   2. proj GEMM: 256x256-tile, BK=64, 512-thr 8-wave 4-phase pipelined kernel
//      (T2 LDS XOR-swizzle + T3/T4 spread staging w/ single counted drain per
//      K-tile + T5 setprio + T1 XCD swizzle).  proj[4096][6144] = xb @ wcat^T.
//   3. transpose v slice -> vt[(b,h)][dim][token]  (plain layout)
//   4. attention, SPLIT-STREAM (R3 structure, unchanged): each 256-thr block
//      computes ONE score stream for one qblk; reg-prefetch -> LDS staging,
//      S^T = K Q^T, tree max, defer-rescale (T13), row-sum via ones-MFMA,
//      PV O^T += V^T P^T; writes normalized a_s = (P/l)V as fp16.
//   4b. combine: y = a1 - lam_h*a2, subLN over 128, *(1-LI), bf16 -> yln.
//   5. out GEMM: out[4096][1024] fp32 = yln @ wc^T  (BN=64 tiles, 512 blocks)
// MFMA mappings (HW-verified): A[m=lane&15][k=quad*8+j] (K=32) / quad*4+j
// (K=16); B^T[n=lane&15][k=same]; C/D: col=lane&15, row=quad*4+reg.
// R8 lesson: #else of the MFMA16 guard must be host-safe.
// R9 lesson: attn LDS bank conflicts are the b64/b128 aliasing floor — but
// gemm_bt's 6.29M conflicts were the REAL T2 target (stride-128B frag reads).
// R10 lesson (R2): no-LDS direct-global attn regressed (latency exposed).
// R11 lesson (R3): split-stream attn worked; proj GEMM became top kernel at
// 646 TF = m97-structure ceiling territory -> this round ports it to the
// 256^2 pipelined template. Swizzle algebra: LDS(row, granule g) holds
// global granule g ^ (row&7); ds_read XORs byte offset with (l16&7)<<4.
// ---------------------------------------------------------------------------

#define T_SEQ 1024
#define NH 16
#define DV 128
#define NPROJ 6144
#define KSTR 72  // attn K/V LDS row stride (elements)

typedef __bf16 bf16_t;
typedef __bf16 bf16x8 __attribute__((ext_vector_type(8)));
typedef __bf16 bf16x4 __attribute__((ext_vector_type(4)));
typedef __bf16 bf16x2 __attribute__((ext_vector_type(2)));
typedef _Float16 f16x4 __attribute__((ext_vector_type(4)));
typedef _Float16 f16x2 __attribute__((ext_vector_type(2)));
typedef short s16x4 __attribute__((ext_vector_type(4)));
typedef float f32x4 __attribute__((ext_vector_type(4)));

#define LAMBDA_INIT 0.35550906759096928f
#define ONE_MINUS_LI 0.6444909324090307f
#define LOG2E 1.4426950408889634f
// defer-rescale threshold in RAW score units: 8 / (0.125*log2e) ~= 44.36
#define RTHR 44.36f

#if __has_builtin(__builtin_amdgcn_mfma_f32_16x16x16_bf16)
#define MFMA16(a, b, c) __builtin_amdgcn_mfma_f32_16x16x16_bf16(a, b, c, 0, 0, 0)
#elif __has_builtin(__builtin_amdgcn_mfma_f32_16x16x16bf16_1k)
#define MFMA16(a, b, c)                                                       \
  __builtin_amdgcn_mfma_f32_16x16x16bf16_1k(                                  \
      __builtin_bit_cast(s16x4, a), __builtin_bit_cast(s16x4, b), c, 0, 0, 0)
#else
#define MFMA16(a, b, c) (c)  // host pass only — never executed
#endif

#define MFMA32(a, b, c) __builtin_amdgcn_mfma_f32_16x16x32_bf16(a, b, c, 0, 0, 0)

// async global->LDS, 16B/lane.
#define GLDS(g, l)                                                            \
  __builtin_amdgcn_global_load_lds(                                           \
      (const __attribute__((address_space(1))) void*)(g),                     \
      (__attribute__((address_space(3))) void*)(l), 16, 0, 0)

// ---------------- workspace layout (bytes) ----------------
static const size_t OFF_WCAT = 0;                                  // 6144x1024 bf16
static const size_t OFF_XB = OFF_WCAT + (size_t)6144 * 1024 * 2;   // 4096x1024 bf16
static const size_t OFF_WCT = OFF_XB + (size_t)4096 * 1024 * 2;    // 1024x2048 bf16
static const size_t OFF_PROJ = OFF_WCT + (size_t)2048 * 1024 * 2;  // 4096x6144 bf16
static const size_t OFF_VT = OFF_PROJ + (size_t)4096 * 6144 * 2;   // 64*128*1024 bf16
static const size_t OFF_YLN = OFF_VT + (size_t)64 * 128 * 1024 * 2;// 4096x2048 bf16
static const size_t OFF_LAM = OFF_YLN + (size_t)4096 * 2048 * 2;   // 16 f32
// a1 (fp16, 16.78 MB) aliases YLN (combine rewrites in place); a2 aliases
// WCAT+XB (dead after proj GEMM).

// ---------------- elementwise cast x -> bf16 ----------------
__global__ void __launch_bounds__(256) cast_x(const float* __restrict__ x,
                                              bf16_t* __restrict__ o) {
  const int i = (blockIdx.x * 256 + threadIdx.x) * 4;
  float4 v = *(const float4*)(x + i);
  bf16x4 r = {(bf16_t)v.x, (bf16_t)v.y, (bf16_t)v.z, (bf16_t)v.w};
  *(bf16x4*)(o + i) = r;
}

// ---------------- transpose-cast weight W[K][N] fp32 -> Wt[row0+n][k] bf16 ----
__device__ __forceinline__ void tcast_body(const float* __restrict__ W,
                                           bf16_t* __restrict__ Wt, int K,
                                           int N, int row0) {
  __shared__ float tile[32][33];
  const int k0 = blockIdx.x * 32, n0 = blockIdx.y * 32;
  const int tx = threadIdx.x & 31, ty = threadIdx.x >> 5;  // 32x8
#pragma unroll
  for (int i = 0; i < 32; i += 8)
    tile[ty + i][tx] = W[(long)(k0 + ty + i) * N + n0 + tx];
  __syncthreads();
#pragma unroll
  for (int i = 0; i < 32; i += 8)
    Wt[(long)(row0 + n0 + ty + i) * K + k0 + tx] = (bf16_t)tile[tx][ty + i];
}

__global__ void __launch_bounds__(256) tcast_w(const float* __restrict__ W,
                                               bf16_t* __restrict__ Wt, int K,
                                               int N, int row0) {
  tcast_body(W, Wt, K, N, row0);
}

// fused: the four 1024x1024 q/k weights in one launch (z selects)
__global__ void __launch_bounds__(256) tcast_w4(const float* __restrict__ W0,
                                                const float* __restrict__ W1,
                                                const float* __restrict__ W2,
                                                const float* __restrict__ W3,
                                                bf16_t* __restrict__ Wt) {
  const float* Ws[4] = {W0, W1, W2, W3};
  tcast_body(Ws[blockIdx.z], Wt, 1024, 1024, blockIdx.z * 1024);
}

// ---------------- per-head lambda ----------------
__global__ void lam_kernel(const float* __restrict__ lq1,
                           const float* __restrict__ lk1,
                           const float* __restrict__ lq2,
                           const float* __restrict__ lk2,
                           float* __restrict__ lam) {
  const int h = threadIdx.x;
  if (h < NH) {
    float d1 = 0.f, d2 = 0.f;
    for (int i = 0; i < 64; ++i) {
      d1 += lq1[h * 64 + i] * lk1[h * 64 + i];
      d2 += lq2[h * 64 + i] * lk2[h * 64 + i];
    }
    lam[h] = expf(d1) - expf(d2) + LAMBDA_INIT;
  }
}

// ---------------- proj GEMM: 256x256 tile, BK=64, 8 waves, pipelined --------
// C[M][N] bf16 = A[M][K] @ Bt[N][K]^T.  grid.x = (M/256)*(N/256), %8 == 0.
// LDS: 2 K-tile buffers (A 256x64 + B 256x64 each) = 128 KiB.  Staging for
// tile t+1 goes into buf^1 (fully dead this iteration -> race-free), issued
// in phases 0-1, drained by ONE vmcnt(0)+barrier at the tile boundary (the
// issue->wait distance is ~3 phases of MFMA, so the drain is cheap).
// T2 swizzle: LDS granule g of row r holds global granule g^(r&7); reads XOR
// the byte offset with (l16&7)<<4 -> stride-128B frag reads become 2-way.
#define GBM 256
#define GBN 256
#define GBK 64

__global__ void __launch_bounds__(512, 1) gemm256(const bf16_t* __restrict__ A,
                                                  const bf16_t* __restrict__ Bt,
                                                  bf16_t* __restrict__ C,
                                                  int M, int N, int K,
                                                  int nbx) {
  __shared__ __align__(16) bf16_t As[2][GBM * GBK];
  __shared__ __align__(16) bf16_t Bs[2][GBN * GBK];
  const int tid = threadIdx.x;
  const int w = tid >> 6, lane = tid & 63;
  const int quad = lane >> 4, l16 = lane & 15;
  const int wr = w >> 2, wc = w & 3;  // 2M x 4N wave grid; wave tile 128x64

  // ---- bijective XCD swizzle (grid % 8 == 0) ----
  const int wg = blockIdx.x;
  const int cpx = gridDim.x >> 3;
  const int sw = (wg & 7) * cpx + (wg >> 3);
  const int by = sw / nbx, bx = sw % nbx;
  const int m0 = by * GBM, n0 = bx * GBN;

  // ---- staging source pointers: lane (r8,g) sources granule g^r8 ----
  const int r8 = lane >> 3, g = lane & 7;
  const int gsw = (g ^ r8) * 8;  // element offset of swizzled 16B granule
  const bf16_t* gA[4];
  const bf16_t* gB[4];
#pragma unroll
  for (int j = 0; j < 4; ++j) {
    gA[j] = A + (long)(m0 + w * 32 + j * 8 + r8) * K + gsw;
    gB[j] = Bt + (long)(n0 + w * 32 + j * 8 + r8) * K + gsw;
  }

  // ---- ds_read swizzled byte offsets (per-lane constant) ----
  const int kx = (l16 & 7) << 4;
  const int ko0 = (quad * 16) ^ kx;       // k-slice 0 (k=0..31)
  const int ko1 = (64 + quad * 16) ^ kx;  // k-slice 1 (k=32..63)

  f32x4 acc[8][4] = {};  // [mt][nt]

  const int nt = K >> 6;

  // ---- prologue: stage tile 0 into buf0 ----
#pragma unroll
  for (int j = 0; j < 4; ++j) {
    GLDS(gA[j], As[0] + (w * 32 + j * 8) * GBK);
    GLDS(gB[j], Bs[0] + (w * 32 + j * 8) * GBK);
  }
  asm volatile("s_waitcnt vmcnt(0)" ::: "memory");
  __builtin_amdgcn_s_barrier();

  for (int t = 0; t < nt; ++t) {
    const bf16_t* Ab = (t & 1) ? As[1] : As[0];
    const bf16_t* Bb = (t & 1) ? Bs[1] : Bs[0];
    bf16_t* Asb = (t & 1) ? As[0] : As[1];
    bf16_t* Bsb = (t & 1) ? Bs[0] : Bs[1];
    const bool pf = (t + 1 < nt);
    const long ko = (long)(t + 1) * GBK;

    const char* Arow = (const char*)Ab + (size_t)(wr * 128 + l16) * 128;
    const char* Brow = (const char*)Bb + (size_t)(wc * 64 + l16) * 128;

    bf16x8 af[4][2], bn0[2][2], bn1[2][2];

    // ---------------- phase 0: A m-half0 + B n-half0; stage j=0,1 ----------
#pragma unroll
    for (int mt = 0; mt < 4; ++mt) {
      af[mt][0] = *(const bf16x8*)(Arow + (size_t)mt * 16 * 128 + ko0);
      af[mt][1] = *(const bf16x8*)(Arow + (size_t)mt * 16 * 128 + ko1);
    }
#pragma unroll
    for (int n = 0; n < 2; ++n) {
      bn0[n][0] = *(const bf16x8*)(Brow + (size_t)n * 16 * 128 + ko0);
      bn0[n][1] = *(const bf16x8*)(Brow + (size_t)n * 16 * 128 + ko1);
    }
    if (pf) {
      GLDS(gA[0] + ko, Asb + (w * 32) * GBK);
      GLDS(gB[0] + ko, Bsb + (w * 32) * GBK);
      GLDS(gA[1] + ko, Asb + (w * 32 + 8) * GBK);
      GLDS(gB[1] + ko, Bsb + (w * 32 + 8) * GBK);
    }
    __builtin_amdgcn_s_barrier();
    __builtin_amdgcn_s_setprio(1);
#pragma unroll
    for (int mt = 0; mt < 4; ++mt)
#pragma unroll
      for (int n = 0; n < 2; ++n) {
        acc[mt][n] = MFMA32(af[mt][0], bn0[n][0], acc[mt][n]);
        acc[mt][n] = MFMA32(af[mt][1], bn0[n][1], acc[mt][n]);
      }
    __builtin_amdgcn_s_setprio(0);
    __builtin_amdgcn_s_barrier();

    // ---------------- phase 1: B n-half1; stage j=2,3 ----------------------
#pragma unroll
    for (int n = 0; n < 2; ++n) {
      bn1[n][0] = *(const bf16x8*)(Brow + (size_t)(32 + n * 16) * 128 + ko0);
      bn1[n][1] = *(const bf16x8*)(Brow + (size_t)(32 + n * 16) * 128 + ko1);
    }
    if (pf) {
      GLDS(gA[2] + ko, Asb + (w * 32 + 16) * GBK);
      GLDS(gB[2] + ko, Bsb + (w * 32 + 16) * GBK);
      GLDS(gA[3] + ko, Asb + (w * 32 + 24) * GBK);
      GLDS(gB[3] + ko, Bsb + (w * 32 + 24) * GBK);
    }
    __builtin_amdgcn_s_barrier();
    __builtin_amdgcn_s_setprio(1);
#pragma unroll
    for (int mt = 0; mt < 4; ++mt)
#pragma unroll
      for (int n = 0; n < 2; ++n) {
        acc[mt][2 + n] = MFMA32(af[mt][0], bn1[n][0], acc[mt][2 + n]);
        acc[mt][2 + n] = MFMA32(af[mt][1], bn1[n][1], acc[mt][2 + n]);
      }
    __builtin_amdgcn_s_setprio(0);
    __builtin_amdgcn_s_barrier();

    // ---------------- phase 2: A m-half1 (overwrite af) --------------------
#pragma unroll
    for (int mt = 0; mt < 4; ++mt) {
      af[mt][0] = *(const bf16x8*)(Arow + (size_t)(64 + mt * 16) * 128 + ko0);
      af[mt][1] = *(const bf16x8*)(Arow + (size_t)(64 + mt * 16) * 128 + ko1);
    }
    __builtin_amdgcn_s_barrier();
    __builtin_amdgcn_s_setprio(1);
#pragma unroll
    for (int mt = 0; mt < 4; ++mt)
#pragma unroll
      for (int n = 0; n < 2; ++n) {
        acc[4 + mt][2 + n] = MFMA32(af[mt][0], bn1[n][0], acc[4 + mt][2 + n]);
        acc[4 + mt][2 + n] = MFMA32(af[mt][1], bn1[n][1], acc[4 + mt][2 + n]);
      }
    __builtin_amdgcn_s_setprio(0);
    __builtin_amdgcn_s_barrier();

    // ---------------- phase 3: (regs only) ---------------------------------
    __builtin_amdgcn_s_setprio(1);
#pragma unroll
    for (int mt = 0; mt < 4; ++mt)
#pragma unroll
      for (int n = 0; n < 2; ++n) {
        acc[4 + mt][n] = MFMA32(af[mt][0], bn0[n][0], acc[4 + mt][n]);
        acc[4 + mt][n] = MFMA32(af[mt][1], bn0[n][1], acc[4 + mt][n]);
      }
    __builtin_amdgcn_s_setprio(0);

    // ---- K-tile boundary: staged loads landed + all waves done reading ----
    asm volatile("s_waitcnt vmcnt(0)" ::: "memory");
    __builtin_amdgcn_s_barrier();
  }

  // ---- epilogue: C-write ----
#pragma unroll
  for (int mt = 0; mt < 8; ++mt)
#pragma unroll
    for (int n = 0; n < 4; ++n) {
      const int col = n0 + wc * 64 + n * 16 + l16;
#pragma unroll
      for (int i = 0; i < 4; ++i) {
        const int row = m0 + wr * 128 + mt * 16 + quad * 4 + i;
        C[(long)row * N + col] = (bf16_t)acc[mt][n][i];
      }
    }
}

// ---------------- GEMM, BN=64 m97-style (out: M=4096 N=1024 -> 512 blocks) --
#define BM 128
#define BK 32

template <typename OutT>
__global__ void __launch_bounds__(256) gemm_bt_n64(const bf16_t* __restrict__ A,
                                                   const bf16_t* __restrict__ Bt,
                                                   OutT* __restrict__ C, int M,
                                                   int N, int K) {
  __shared__ __align__(16) bf16_t As[BM * BK];
  __shared__ __align__(16) bf16_t Bs[64 * BK];
  const int tid = threadIdx.x;
  const int w = tid >> 6;
  const int lane = tid & 63;
  const int quad = lane >> 4, l16 = lane & 15;
  const int m0 = blockIdx.y * BM, n0 = blockIdx.x * 64;
  const int wm = (w >> 1) * 64, wn = (w & 1) * 32;
  const int srow = tid >> 2;       // 0..63
  const int scol = (tid & 3) * 8;  // 0,8,16,24

  const bf16_t* Ag0 = A + (long)(m0 + srow) * K + scol;
  const bf16_t* Ag1 = Ag0 + (long)64 * K;
  const bf16_t* Bg0 = Bt + (long)(n0 + srow) * K + scol;
  bf16_t* lA0 = As + tid * 8;
  bf16_t* lA1 = As + 2048 + tid * 8;
  bf16_t* lB0 = Bs + tid * 8;

  f32x4 acc[4][2] = {};

  for (int k0 = 0; k0 < K; k0 += BK) {
    GLDS(Ag0 + k0, lA0);
    GLDS(Ag1 + k0, lA1);
    GLDS(Bg0 + k0, lB0);
    __syncthreads();
    bf16x8 af[4], bfr[2];
#pragma unroll
    for (int t = 0; t < 4; ++t)
      af[t] = *(const bf16x8*)(As + (wm + t * 16 + l16) * BK + quad * 8);
#pragma unroll
    for (int t = 0; t < 2; ++t)
      bfr[t] = *(const bf16x8*)(Bs + (wn + t * 16 + l16) * BK + quad * 8);
#pragma unroll
    for (int mt = 0; mt < 4; ++mt)
#pragma unroll
      for (int ntt = 0; ntt < 2; ++ntt)
        acc[mt][ntt] = MFMA32(af[mt], bfr[ntt], acc[mt][ntt]);
    __syncthreads();
  }

#pragma unroll
  for (int mt = 0; mt < 4; ++mt)
#pragma unroll
    for (int ntt = 0; ntt < 2; ++ntt) {
      const int col = n0 + wn + ntt * 16 + l16;
#pragma unroll
      for (int i = 0; i < 4; ++i) {
        const int row = m0 + wm + mt * 16 + quad * 4 + i;
        C[(long)row * N + col] = (OutT)acc[mt][ntt][i];
      }
    }
}

// ---------------- transpose v slice of proj -> vt[(b,h)][d][t] (plain) -------
__global__ void __launch_bounds__(256) transpose_v(const bf16_t* __restrict__ proj,
                                                   bf16_t* __restrict__ vt) {
  __shared__ bf16_t tile[32][34];
  const int bh = blockIdx.z;
  const int b = bh >> 4, h = bh & 15;
  const int t0 = blockIdx.x * 32, d0 = blockIdx.y * 32;
  const int tx = threadIdx.x & 31, ty = threadIdx.x >> 5;
  const bf16_t* src = proj + (long)(b * T_SEQ) * NPROJ + 4096 + h * 128;
#pragma unroll
  for (int i = 0; i < 32; i += 8)
    tile[ty + i][tx] = src[(long)(t0 + ty + i) * NPROJ + d0 + tx];
  __syncthreads();
  bf16_t* dst = vt + ((long)bh * DV) * T_SEQ;
#pragma unroll
  for (int i = 0; i < 32; i += 8)
    dst[(long)(d0 + ty + i) * T_SEQ + t0 + tx] = tile[tx][ty + i];
}

// ---------------- attention: split-stream, one (qblk, stream) per block ------
// grid: (2048). x>>7 = qi (qblk = 15-qi, big first / LPT), st = (x>>6)&1,
// bh = x&63 (x%8 tracks bh -> same-(b,h) blocks share an XCD's L2).
// 4 waves; wave w owns q rows q0..q0+15 (q = lane&15 for all fragments).
__global__ void __launch_bounds__(256) attn_kernel(const bf16_t* __restrict__ proj,
                                                   const bf16_t* __restrict__ vt,
                                                   _Float16* __restrict__ a1,
                                                   _Float16* __restrict__ a2) {
  const int x = blockIdx.x;
  const int qblk = 15 - (x >> 7);
  const int st = (x >> 6) & 1;
  const int bh = x & 63;
  const int b = bh >> 4, h = bh & 15;
  const int tid = threadIdx.x;
  const int w = tid >> 6, lane = tid & 63;
  const int quad = lane >> 4, l16 = lane & 15;
  const long bT = (long)b * T_SEQ;

  __shared__ __align__(16) bf16_t Ks[64 * KSTR];  // [key][dim]
  __shared__ __align__(16) bf16_t Vs[DV * KSTR];  // [dim][key]

  // ---- staging source pointers (this stream's K; shared V) ----
  const int koff = h * 64 + 2048 + st * 1024;
  const bf16_t* gK = proj + (bT + (tid >> 2)) * (long)NPROJ + koff + (tid & 3) * 16;
  const bf16_t* gV = vt + (long)bh * DV * T_SEQ + (long)(tid >> 1) * T_SEQ +
                     (tid & 1) * 32;
  const int kwK = (tid >> 2) * KSTR + (tid & 3) * 16;
  const int kwV = (tid >> 1) * KSTR + (tid & 1) * 32;

  const float sc = 0.125f * LOG2E;  // 1/sqrt(64) folded with log2(e)
  const int q0 = qblk * 64 + w * 16;
  const int qg = q0 + l16;  // this lane's q row (all fragments)

  // ---- Q fragments (B-operand role), this stream only ----
  const bf16_t* qrow = proj + (bT + qg) * (long)NPROJ + h * 64 + st * 1024;
  bf16x8 aq[2];
  aq[0] = *(const bf16x8*)(qrow + quad * 8);
  aq[1] = *(const bf16x8*)(qrow + 32 + quad * 8);

  f32x4 O[8] = {};  // O^T[d=f*16+quad*4+reg][q=l16]
  float m = -3.0e38f, l = 0.f;
  const bf16x4 one4 = {(bf16_t)1.0f, (bf16_t)1.0f, (bf16_t)1.0f, (bf16_t)1.0f};

  const int kend_blk = qblk * 64 + 64;
  const int kend_w = q0 + 16;

  // ---- prime the register pipeline with tile kt=0 ----
  bf16x8 rK[2], rV[4];
  rK[0] = *(const bf16x8*)(gK);
  rK[1] = *(const bf16x8*)(gK + 8);
#pragma unroll
  for (int j = 0; j < 4; ++j) rV[j] = *(const bf16x8*)(gV + j * 8);

  for (int kt = 0; kt < kend_blk; kt += 64) {
    // ---- commit staged registers to LDS ----
    *(bf16x8*)(Ks + kwK) = rK[0];
    *(bf16x8*)(Ks + kwK + 8) = rK[1];
#pragma unroll
    for (int j = 0; j < 4; ++j) *(bf16x8*)(Vs + kwV + j * 8) = rV[j];
    __syncthreads();

    // ---- prefetch next tile into registers (overlaps compute) ----
    if (kt + 64 < kend_blk) {
      const long ko = (long)(kt + 64) * NPROJ;
      rK[0] = *(const bf16x8*)(gK + ko);
      rK[1] = *(const bf16x8*)(gK + ko + 8);
#pragma unroll
      for (int j = 0; j < 4; ++j)
        rV[j] = *(const bf16x8*)(gV + kt + 64 + j * 8);
    }

    if (kt < kend_w) {
      // ---- S^T = K Q^T : A=K-frag (from LDS), B=Q-frag (regs) ----
      f32x4 s[4];
#pragma unroll
      for (int c = 0; c < 4; ++c) {
        const bf16_t* kr = Ks + (c * 16 + l16) * KSTR;
        bf16x8 ka0 = *(const bf16x8*)(kr + quad * 8);
        bf16x8 ka1 = *(const bf16x8*)(kr + 32 + quad * 8);
        f32x4 z = {};
        z = MFMA32(ka0, aq[0], z);
        z = MFMA32(ka1, aq[1], z);
        s[c] = z;
      }
      // ---- causal mask (diagonal tile only) + in-lane TREE max ----
      if (kt + 63 > q0) {
#pragma unroll
        for (int c = 0; c < 4; ++c)
#pragma unroll
          for (int i = 0; i < 4; ++i) {
            const int key = kt + c * 16 + quad * 4 + i;
            if (key > qg) s[c][i] = -1e30f;
          }
      }
      float t[4];
#pragma unroll
      for (int c = 0; c < 4; ++c)
        t[c] = fmaxf(fmaxf(s[c][0], s[c][1]), fmaxf(s[c][2], s[c][3]));
      float mx = fmaxf(fmaxf(t[0], t[1]), fmaxf(t[2], t[3]));
      mx = fmaxf(mx, __shfl_xor(mx, 16));
      mx = fmaxf(mx, __shfl_xor(mx, 32));
      // ---- defer-rescale (T13) ----
      if (!__all(mx <= m + RTHR)) {
        const float mn = fmaxf(m, mx);
        const float al = exp2f((m - mn) * sc);
        m = mn;
#pragma unroll
        for (int f = 0; f < 8; ++f)
#pragma unroll
          for (int i = 0; i < 4; ++i) O[f][i] *= al;
        l *= al;
      }
      // ---- P = exp2(fma(s,sc,-m*sc)), packed bf16x4 per c ----
      const float ms = m * sc;
      bf16x4 pc[4];
#pragma unroll
      for (int c = 0; c < 4; ++c)
#pragma unroll
        for (int i = 0; i < 4; ++i)
          pc[c][i] = (bf16_t)exp2f(fmaf(s[c][i], sc, -ms));
      // ---- row-sum l via ones-row MFMA ----
      f32x4 la = {};
#pragma unroll
      for (int c = 0; c < 4; ++c) la = MFMA16(one4, pc[c], la);
      // ---- PV: O^T += V^T P^T ----
#pragma unroll
      for (int c = 0; c < 4; ++c) {
#pragma unroll
        for (int f = 0; f < 8; ++f) {
          bf16x4 va =
              *(const bf16x4*)(Vs + (f * 16 + l16) * KSTR + c * 16 + quad * 4);
          O[f] = MFMA16(va, pc[c], O[f]);
        }
      }
      l += la[0];
    }
    __syncthreads();
  }

  // ---- normalize and store per-stream a_s = (P/l)V as fp16 ----
  const float inv = 1.0f / l;
  _Float16* ob = st ? a2 : a1;
  _Float16* dst = ob + ((bT + qg) * 16 + h) * (long)128 + quad * 4;
#pragma unroll
  for (int f = 0; f < 8; ++f) {
    f16x4 o = {(_Float16)(O[f][0] * inv), (_Float16)(O[f][1] * inv),
               (_Float16)(O[f][2] * inv), (_Float16)(O[f][3] * inv)};
    *(f16x4*)(dst + f * 16) = o;
  }
}

// ---------------- combine: y = a1 - lam*a2, subLN(128), *(1-LI) -> bf16 ------
__global__ void __launch_bounds__(256) combine_kernel(const _Float16* __restrict__ a1,
                                                      const _Float16* __restrict__ a2,
                                                      const float* __restrict__ lamp,
                                                      bf16_t* __restrict__ yln) {
  const int unit = blockIdx.x * 4 + (threadIdx.x >> 6);  // 0..65535 = r*16+h
  const int lane = threadIdx.x & 63;
  const float lam = lamp[unit & 15];
  const long base = (long)unit * 128 + lane * 2;
  f16x2 v1 = *(const f16x2*)(a1 + base);
  f16x2 v2 = *(const f16x2*)(a2 + base);
  float y0 = (float)v1[0] - lam * (float)v2[0];
  float y1 = (float)v1[1] - lam * (float)v2[1];
  float sm = y0 + y1, sq = y0 * y0 + y1 * y1;
#pragma unroll
  for (int off = 1; off < 64; off <<= 1) {
    sm += __shfl_xor(sm, off);
    sq += __shfl_xor(sq, off);
  }
  const float mu = sm * (1.0f / 128.0f);
  const float var = sq * (1.0f / 128.0f) - mu * mu;
  const float rs = rsqrtf(var + 1e-5f) * ONE_MINUS_LI;
  bf16x2 o = {(bf16_t)((y0 - mu) * rs), (bf16_t)((y1 - mu) * rs)};
  *(bf16x2*)(yln + base) = o;
}

// ---------------------------------------------------------------------------
extern "C" void kernel_launch(void* const* d_in, const int* in_sizes, int n_in,
                              void* d_out, int out_size, void* d_ws,
                              size_t ws_size, hipStream_t stream) {
  const float* x = (const float*)d_in[0];
  const float* Wq1 = (const float*)d_in[1];
  const float* Wq2 = (const float*)d_in[2];
  const float* Wk1 = (const float*)d_in[3];
  const float* Wk2 = (const float*)d_in[4];
  const float* Wv = (const float*)d_in[5];
  const float* Wc = (const float*)d_in[6];
  const float* lq1 = (const float*)d_in[7];
  const float* lk1 = (const float*)d_in[8];
  const float* lq2 = (const float*)d_in[9];
  const float* lk2 = (const float*)d_in[10];
  float* out = (float*)d_out;

  char* ws = (char*)d_ws;
  bf16_t* wcat = (bf16_t*)(ws + OFF_WCAT);
  bf16_t* xb = (bf16_t*)(ws + OFF_XB);
  bf16_t* wct = (bf16_t*)(ws + OFF_WCT);
  bf16_t* projb = (bf16_t*)(ws + OFF_PROJ);
  bf16_t* vtb = (bf16_t*)(ws + OFF_VT);
  bf16_t* ylnb = (bf16_t*)(ws + OFF_YLN);
  float* lamp = (float*)(ws + OFF_LAM);
  _Float16* a1b = (_Float16*)(ws + OFF_YLN);   // aliases yln (in-place combine)
  _Float16* a2b = (_Float16*)(ws + OFF_WCAT);  // aliases wcat+xb (dead after proj)

  cast_x<<<4096, 256, 0, stream>>>(x, xb);
  tcast_w4<<<dim3(32, 32, 4), 256, 0, stream>>>(Wq1, Wq2, Wk1, Wk2, wcat);
  tcast_w<<<dim3(32, 64), 256, 0, stream>>>(Wv, wcat, 1024, 2048, 4096);
  tcast_w<<<dim3(64, 32), 256, 0, stream>>>(Wc, wct, 2048, 1024, 0);
  lam_kernel<<<1, 64, 0, stream>>>(lq1, lk1, lq2, lk2, lamp);

  // proj = xb @ wcat^T : M=4096 N=6144 K=1024 ; 16x24 = 384 tiles (384%8==0)
  gemm256<<<dim3(384), 512, 0, stream>>>(xb, wcat, projb, 4096, 6144, 1024, 24);
  transpose_v<<<dim3(32, 4, 64), 256, 0, stream>>>(projb, vtb);
  attn_kernel<<<dim3(2048), 256, 0, stream>>>(projb, vtb, a1b, a2b);
  combine_kernel<<<dim3(16384), 256, 0, stream>>>(a1b, a2b, lamp, ylnb);
  // out = yln @ wc^T : M=4096 N=1024 K=2048  (BN=64 -> 512 blocks)
  gemm_bt_n64<float><<<dim3(16, 32), 256, 0, stream>>>(ylnb, wct, out, 4096, 1024, 2048);
}